// Round 1
// baseline (224.800 us; speedup 1.0000x reference)
//
#include <hip/hip_runtime.h>

#define NB    1024
#define LQ    20
#define LD    200
#define EDIM  128
#define E4    32      // EDIM/4
#define NK    21
#define NPRED 2
#define NCOLS 400     // 2 preds * LD
#define NQR   40      // 2 preds * LQ

__global__ __launch_bounds__(256, 2) void knrm_kernel(
    const int* __restrict__ q1, const int* __restrict__ d1,
    const int* __restrict__ q2, const int* __restrict__ d2,
    const float* __restrict__ emb,
    const float* __restrict__ W1, const float* __restrict__ b1,
    const float* __restrict__ W2, const float* __restrict__ b2,
    const float* __restrict__ W3, const float* __restrict__ b3,
    float* __restrict__ out)
{
    __shared__ float4 sQ4[NQR][E4];     // 20 KB: raw q embeddings (broadcast reads)
    __shared__ float  sQsq[NQR];
    __shared__ float  sQrn[NQR];
    __shared__ float  sM[NCOLS][NK];    // 33.6 KB: M transposed staging (stride 21 = pad)
    __shared__ float  sPhi[NQR][NK];    // per-(pred,i) kernel sums
    __shared__ float  sX[NPRED * NK];
    __shared__ float  sH1[NPRED * 10];
    __shared__ float  sH2[NPRED * 5];
    __shared__ float  sL[NPRED];

    const int b = blockIdx.x;
    const int t = threadIdx.x;
    const float4* emb4 = (const float4*)emb;

    // ---- init LDS accumulators ----
    if (t < NQR) sQsq[t] = 0.f;
    for (int p = t; p < NQR * NK; p += 256) ((float*)sPhi)[p] = 0.f;
    __syncthreads();

    // ---- Phase A: stage q rows into LDS + sumsq ----
    {
        const int sub = t & 7;               // 8 threads per row
        for (int r = (t >> 3); r < NQR; r += 32) {
            const int pred = r / LQ, i = r % LQ;
            const int id = pred ? q2[b * LQ + i] : q1[b * LQ + i];
            const float4* src = emb4 + (size_t)id * E4;
            float s = 0.f;
            #pragma unroll
            for (int u = 0; u < 4; ++u) {
                float4 v = src[sub + 8 * u];
                sQ4[r][sub + 8 * u] = v;
                s += v.x * v.x + v.y * v.y + v.z * v.z + v.w * v.w;
            }
            atomicAdd(&sQsq[r], s);
        }
    }
    __syncthreads();
    if (t < NQR) sQrn[t] = rsqrtf(sQsq[t] + 1e-6f);
    __syncthreads();

    // ---- Phase B: each thread owns 2 d-columns; M = Q . D / (|q||d|) ----
    if (t < 200) {
        const int cA = 2 * t, cB = 2 * t + 1;
        const int pred = (t < 100) ? 0 : 1;
        const int jA = cA - pred * 200;
        const int* dd = pred ? d2 : d1;
        const int idA = dd[b * LD + jA];
        const int idB = dd[b * LD + jA + 1];
        const float4* pA = emb4 + (size_t)idA * E4;
        const float4* pB = emb4 + (size_t)idB * E4;
        const int qb = pred * LQ;

        float accA[LQ], accB[LQ];
        #pragma unroll
        for (int i = 0; i < LQ; ++i) { accA[i] = 0.f; accB[i] = 0.f; }
        float dsqA = 0.f, dsqB = 0.f;

        for (int e4 = 0; e4 < E4; ++e4) {
            float4 a = pA[e4];
            float4 c = pB[e4];
            dsqA += a.x * a.x + a.y * a.y + a.z * a.z + a.w * a.w;
            dsqB += c.x * c.x + c.y * c.y + c.z * c.z + c.w * c.w;
            #pragma unroll
            for (int i = 0; i < LQ; ++i) {
                float4 q = sQ4[qb + i][e4];   // wave-uniform -> broadcast
                accA[i] += q.x * a.x + q.y * a.y + q.z * a.z + q.w * a.w;
                accB[i] += q.x * c.x + q.y * c.y + q.z * c.z + q.w * c.w;
            }
        }
        const float rdA = rsqrtf(dsqA + 1e-6f);
        const float rdB = rsqrtf(dsqB + 1e-6f);
        #pragma unroll
        for (int i = 0; i < LQ; ++i) {
            const float qr = sQrn[qb + i];
            sM[cA][i] = accA[i] * qr * rdA;
            sM[cB][i] = accB[i] * qr * rdB;
        }
    }
    __syncthreads();

    // ---- Phase C: RBF kernels, sum over j ----
    if (t < 240) {
        const int o = t % 40, slice = t / 40;   // 6 j-slices
        const int pred = o / LQ, i = o % LQ;
        const int j0 = slice * 34;
        const int j1 = (j0 + 34 < LD) ? (j0 + 34) : LD;
        const int cbase = pred * 200;
        float S[NK];
        #pragma unroll
        for (int k = 0; k < NK; ++k) S[k] = 0.f;
        for (int j = j0; j < j1; ++j) {
            const float m = sM[cbase + j][i];
            #pragma unroll
            for (int k = 0; k < NK; ++k) {
                const float mu = (k < 20) ? (-0.95f + 0.1f * (float)k) : 1.0f;
                const float cc = (k < 20) ? -50.0f : -500000.0f;   // -1/(2*sig^2)
                const float d = m - mu;
                S[k] += __expf(d * d * cc);
            }
        }
        #pragma unroll
        for (int k = 0; k < NK; ++k) atomicAdd(&sPhi[o][k], S[k]);
    }
    __syncthreads();

    // ---- log1p + sum over i ----
    if (t < NPRED * NK) {
        const int pred = t / NK, k = t % NK;
        float s = 0.f;
        #pragma unroll
        for (int i = 0; i < LQ; ++i) s += __logf(1.0f + sPhi[pred * LQ + i][k]);
        sX[t] = fmaxf(s, 0.f);   // relu (no-op: s >= 0)
    }
    __syncthreads();

    // ---- MLP layer 1: 21 -> 10 ----
    if (t < NPRED * 10) {
        const int pred = t / 10, h = t % 10;
        float v = b1[h];
        #pragma unroll
        for (int k = 0; k < NK; ++k) v += W1[h * NK + k] * sX[pred * NK + k];
        sH1[t] = fmaxf(v, 0.f);
    }
    __syncthreads();

    // ---- MLP layer 2: 10 -> 5 ----
    if (t < NPRED * 5) {
        const int pred = t / 5, h = t % 5;
        float v = b2[h];
        #pragma unroll
        for (int k = 0; k < 10; ++k) v += W2[h * 10 + k] * sH1[pred * 10 + k];
        sH2[t] = fmaxf(v, 0.f);
    }
    __syncthreads();

    // ---- MLP layer 3: 5 -> 1 ----
    if (t < NPRED) {
        float v = b3[0];
        #pragma unroll
        for (int k = 0; k < 5; ++k) v += W3[k] * sH2[t * 5 + k];
        sL[t] = v;
    }
    __syncthreads();

    if (t == 0) out[b] = 1.0f / (1.0f + __expf(sL[1] - sL[0]));
}

extern "C" void kernel_launch(void* const* d_in, const int* in_sizes, int n_in,
                              void* d_out, int out_size, void* d_ws, size_t ws_size,
                              hipStream_t stream) {
    knrm_kernel<<<NB, 256, 0, stream>>>(
        (const int*)d_in[0], (const int*)d_in[1],
        (const int*)d_in[2], (const int*)d_in[3],
        (const float*)d_in[4],
        (const float*)d_in[5], (const float*)d_in[6],
        (const float*)d_in[7], (const float*)d_in[8],
        (const float*)d_in[9], (const float*)d_in[10],
        (float*)d_out);
}